// Round 1
// baseline (337.336 us; speedup 1.0000x reference)
//
#include <hip/hip_runtime.h>
#include <math.h>

// GradLoss over (B=8, C=4, D=64, H=128, W=128) fp32 tensors.
// out = sum over axes {D,H,W} of sum_c mean_{b,d,h,w} (grad(x)-grad(t))^2
// (clean() dropped: |g|<1e-6 zeroing perturbs the total ~1e-9, verified in a
//  previous round with absmax 0.0.)
//
// R5: latency-bound fix. Old structure loaded 6 float4/step/thread (center
// row h+1 plus x,t at d+-1), a 3x vmem-request amplification with a full
// vmcnt drain per step. New structure: u = x - t is formed ONCE per element;
// the current-h u row of every d-plane is published to LDS each step, and the
// D-axis gradient reads u(d+-1) from LDS. Loads drop to 2 float4/step/thread
// (+2 for the 2/8 halo threads). H stays a register sliding window, W stays
// the intra-row shfl. __launch_bounds__(256,8) pins VGPR<=64 so the full
// 8 waves/SIMD residency is kept (cross-step load pipelining is impossible
// anyway: __syncthreads drains vmcnt).

#define Bn 8
#define Cn 4
#define Dn 64
#define Hn 128
#define Wn 128

static constexpr int HCHUNK = 8;             // h-steps per block
static constexpr int NTHREADS = 256;         // w4(32) x dlow(8)
static constexpr int NBLOCKS = 4096;         // bc(32) x hc(16) x dhigh(8)
static constexpr int ROW = Wn / 4;           // 32 float4 per W-row
static constexpr int PLANE = Hn * ROW;       // 4096 float4 per (H,W) plane

__device__ __forceinline__ float4 sub4(const float4 a, const float4 b) {
    float4 r;
    r.x = a.x - b.x; r.y = a.y - b.y;
    r.z = a.z - b.z; r.w = a.w - b.w;
    return r;
}

__global__ __launch_bounds__(NTHREADS, 8) void gradloss_main(
        const float* __restrict__ xf, const float* __restrict__ tf,
        double* __restrict__ partials) {
    const int tid  = threadIdx.x;
    const int w4   = tid & 31;          // float4 index within W-row
    const int dlow = tid >> 5;          // 8 consecutive d-planes per block
    const int b    = blockIdx.x;
    const int bc    = b & 31;           // low bits -> XCD slab ownership
    const int hc    = (b >> 5) & 15;
    const int dhigh = b >> 9;
    const int d  = dhigh * 8 + dlow;
    const int h0 = hc * HCHUNK;

    const int base = ((bc * Dn + d) * Hn + h0) * ROW + w4;  // float4 index
    const float4* __restrict__ Xr = (const float4*)xf + base;
    const float4* __restrict__ Tr = (const float4*)tf + base;

    const bool haloLow  = (dlow == 0);
    const bool haloHigh = (dlow == 7);
    const bool isHalo   = haloLow | haloHigh;
    // Halo plane offset relative to OWN plane (float4 units), clamped at the
    // d-volume edges (clamped halo == own plane => one-sided grad, scale 1).
    const int hoff = haloLow ? ((dhigh > 0) ? -PLANE : 0)
                             : ((dhigh < 7) ?  PLANE : 0);

    const float sd2  = (d == 0 || d == Dn - 1) ? 1.0f : 0.25f;
    const float sw02 = (w4 == 0) ? 1.0f : 0.25f;
    const float sw32 = (w4 == 31) ? 1.0f : 0.25f;

    // u row tile: [buf][d-row 0..9][w4]; rows 1..8 = block planes, 0/9 = halo
    __shared__ float4 uL[2][10][32];

    // ---- prologue: u(h0), u(h0-1), halo u(h0) ----
    float4 uc = sub4(Xr[0], Tr[0]);
    float4 um;
    if (h0 > 0) um = sub4(Xr[-ROW], Tr[-ROW]);   // block-uniform branch
    else        um = uc;
    float4 hu;
    if (isHalo) hu = sub4(Xr[hoff], Tr[hoff]);
    else        hu = make_float4(0.f, 0.f, 0.f, 0.f);

    float acc0 = 0.0f, acc1 = 0.0f, acc2 = 0.0f;
    int s = 0;
    #pragma unroll
    for (int hl = 0; hl < HCHUNK; ++hl) {
        const int h = h0 + hl;
        const int po = (h < Hn - 1) ? ROW : 0;   // block-uniform

        // issue next-row loads (latency overlaps LDS publish + barrier)
        const float4 xn = Xr[po], tn = Tr[po];
        float4 xh, th;
        if (isHalo) { xh = Xr[hoff + po]; th = Tr[hoff + po]; }

        // publish current-row u
        uL[s][dlow + 1][w4] = uc;
        if (haloLow)  uL[s][0][w4] = hu;
        if (haloHigh) uL[s][9][w4] = hu;
        __syncthreads();

        // ---- D axis: u(d+1,h) - u(d-1,h) from LDS ----
        const float4 udp = uL[s][dlow + 2][w4];
        const float4 udm = uL[s][dlow][w4];
        { const float dx = udp.x - udm.x; acc1 = fmaf(dx * dx, sd2, acc1); }
        { const float dx = udp.y - udm.y; acc1 = fmaf(dx * dx, sd2, acc1); }
        { const float dx = udp.z - udm.z; acc1 = fmaf(dx * dx, sd2, acc1); }
        { const float dx = udp.w - udm.w; acc1 = fmaf(dx * dx, sd2, acc1); }

        // ---- W axis: neighbors via shfl on u(h) within 32-lane groups ----
        const float ulw = __shfl_up(uc.w, 1, 32);
        const float urx = __shfl_down(uc.x, 1, 32);
        const float ul = (w4 == 0)  ? uc.x : ulw;
        const float ur = (w4 == 31) ? uc.w : urx;
        { const float dx = uc.y - ul;   acc2 = fmaf(dx * dx, sw02, acc2); }
        { const float dx = uc.z - uc.x; acc2 = fmaf(dx * dx, 0.25f, acc2); }
        { const float dx = uc.w - uc.y; acc2 = fmaf(dx * dx, 0.25f, acc2); }
        { const float dx = ur - uc.z;   acc2 = fmaf(dx * dx, sw32, acc2); }

        // ---- H axis: u(h+1) - u(h-1) in registers ----
        const float4 un = sub4(xn, tn);
        const float sh2 = (h == 0 || h == Hn - 1) ? 1.0f : 0.25f;
        { const float dx = un.x - um.x; acc0 = fmaf(dx * dx, sh2, acc0); }
        { const float dx = un.y - um.y; acc0 = fmaf(dx * dx, sh2, acc0); }
        { const float dx = un.z - um.z; acc0 = fmaf(dx * dx, sh2, acc0); }
        { const float dx = un.w - um.w; acc0 = fmaf(dx * dx, sh2, acc0); }

        // slide windows
        um = uc; uc = un;
        if (isHalo) hu = sub4(xh, th);
        Xr += ROW; Tr += ROW;
        s ^= 1;
    }

    float acc = (acc0 + acc1) + acc2;

    // wave (64-lane) reduction
    for (int off = 32; off > 0; off >>= 1)
        acc += __shfl_down(acc, off, 64);

    __shared__ float wsum[NTHREADS / 64];
    const int lane = tid & 63;
    const int wid = tid >> 6;
    if (lane == 0) wsum[wid] = acc;
    __syncthreads();
    if (tid == 0) {
        double bsum = (double)wsum[0] + (double)wsum[1] +
                      (double)wsum[2] + (double)wsum[3];
        partials[blockIdx.x] = bsum;
    }
}

__global__ __launch_bounds__(256) void gradloss_reduce(
        const double* __restrict__ partials, float* __restrict__ out, int n) {
    double a = 0.0;
    for (int i = threadIdx.x; i < n; i += 256) a += partials[i];
    for (int off = 32; off > 0; off >>= 1)
        a += __shfl_down(a, off, 64);
    __shared__ double sh[4];
    const int lane = threadIdx.x & 63;
    const int wid = threadIdx.x >> 6;
    if (lane == 0) sh[wid] = a;
    __syncthreads();
    if (threadIdx.x == 0) {
        double tot = sh[0] + sh[1] + sh[2] + sh[3];
        out[0] = (float)(tot / 8388608.0);  // / (B*D*H*W)
    }
}

extern "C" void kernel_launch(void* const* d_in, const int* in_sizes, int n_in,
                              void* d_out, int out_size, void* d_ws, size_t ws_size,
                              hipStream_t stream) {
    const float* x = (const float*)d_in[0];
    const float* t = (const float*)d_in[1];
    float* out = (float*)d_out;
    double* partials = (double*)d_ws;  // NBLOCKS * 8 B = 32 KiB of d_ws

    gradloss_main<<<NBLOCKS, NTHREADS, 0, stream>>>(x, t, partials);
    gradloss_reduce<<<1, 256, 0, stream>>>(partials, out, NBLOCKS);
}

// Round 2
// 284.516 us; speedup vs baseline: 1.1857x; 1.1857x over previous
//
#include <hip/hip_runtime.h>
#include <math.h>

// GradLoss over (B=8, C=4, D=64, H=128, W=128) fp32 tensors.
// out = sum over axes {D,H,W} of sum_c mean_{b,d,h,w} (grad(x)-grad(t))^2
// (clean() dropped: |g|<1e-6 zeroing perturbs the total ~1e-9; absmax 0.0.)
//
// R6: R5 structure (u = x-t formed once; D-axis neighbors via per-row LDS
// tile; 2 float4 loads/step/thread instead of 6) with the spill bug fixed.
// R5's __launch_bounds__(256,8) capped VGPR at 64 -> compiler spilled the
// sliding-window state to scratch: WRITE_SIZE 147 KB -> 168 MB, fetch +123 MB,
// dur 110 -> 158 us. launch_bounds(256,4) caps at 128 VGPR: state (~60-90
// VGPR) fits with zero spill, still allows 16 waves/CU (50% occupancy, above
// the 39% the R4 kernel achieved).

#define Bn 8
#define Cn 4
#define Dn 64
#define Hn 128
#define Wn 128

static constexpr int HCHUNK = 8;             // h-steps per block
static constexpr int NTHREADS = 256;         // w4(32) x dlow(8)
static constexpr int NBLOCKS = 4096;         // bc(32) x hc(16) x dhigh(8)
static constexpr int ROW = Wn / 4;           // 32 float4 per W-row
static constexpr int PLANE = Hn * ROW;       // 4096 float4 per (H,W) plane

__device__ __forceinline__ float4 sub4(const float4 a, const float4 b) {
    float4 r;
    r.x = a.x - b.x; r.y = a.y - b.y;
    r.z = a.z - b.z; r.w = a.w - b.w;
    return r;
}

__global__ __launch_bounds__(NTHREADS, 4) void gradloss_main(
        const float* __restrict__ xf, const float* __restrict__ tf,
        double* __restrict__ partials) {
    const int tid  = threadIdx.x;
    const int w4   = tid & 31;          // float4 index within W-row
    const int dlow = tid >> 5;          // 8 consecutive d-planes per block
    const int b    = blockIdx.x;
    const int bc    = b & 31;           // low bits -> XCD slab ownership
    const int hc    = (b >> 5) & 15;
    const int dhigh = b >> 9;
    const int d  = dhigh * 8 + dlow;
    const int h0 = hc * HCHUNK;

    const int base = ((bc * Dn + d) * Hn + h0) * ROW + w4;  // float4 index
    const float4* __restrict__ Xr = (const float4*)xf + base;
    const float4* __restrict__ Tr = (const float4*)tf + base;

    const bool haloLow  = (dlow == 0);
    const bool haloHigh = (dlow == 7);
    const bool isHalo   = haloLow | haloHigh;
    // Halo plane offset relative to OWN plane (float4 units), clamped at the
    // d-volume edges (clamped halo == own plane => one-sided grad, scale 1).
    const int hoff = haloLow ? ((dhigh > 0) ? -PLANE : 0)
                             : ((dhigh < 7) ?  PLANE : 0);

    const float sd2  = (d == 0 || d == Dn - 1) ? 1.0f : 0.25f;
    const float sw02 = (w4 == 0) ? 1.0f : 0.25f;
    const float sw32 = (w4 == 31) ? 1.0f : 0.25f;

    // u row tile: [buf][d-row 0..9][w4]; rows 1..8 = block planes, 0/9 = halo
    __shared__ float4 uL[2][10][32];

    // ---- prologue: u(h0), u(h0-1), halo u(h0) ----
    float4 uc = sub4(Xr[0], Tr[0]);
    float4 um;
    if (h0 > 0) um = sub4(Xr[-ROW], Tr[-ROW]);   // block-uniform branch
    else        um = uc;
    float4 hu;
    if (isHalo) hu = sub4(Xr[hoff], Tr[hoff]);
    else        hu = make_float4(0.f, 0.f, 0.f, 0.f);

    float acc0 = 0.0f, acc1 = 0.0f, acc2 = 0.0f;
    int s = 0;
    #pragma unroll
    for (int hl = 0; hl < HCHUNK; ++hl) {
        const int h = h0 + hl;
        const int po = (h < Hn - 1) ? ROW : 0;   // block-uniform

        // issue next-row loads (latency overlaps LDS publish + barrier)
        const float4 xn = Xr[po], tn = Tr[po];
        float4 xh, th;
        if (isHalo) { xh = Xr[hoff + po]; th = Tr[hoff + po]; }

        // publish current-row u
        uL[s][dlow + 1][w4] = uc;
        if (haloLow)  uL[s][0][w4] = hu;
        if (haloHigh) uL[s][9][w4] = hu;
        __syncthreads();

        // ---- D axis: u(d+1,h) - u(d-1,h) from LDS ----
        const float4 udp = uL[s][dlow + 2][w4];
        const float4 udm = uL[s][dlow][w4];
        { const float dx = udp.x - udm.x; acc1 = fmaf(dx * dx, sd2, acc1); }
        { const float dx = udp.y - udm.y; acc1 = fmaf(dx * dx, sd2, acc1); }
        { const float dx = udp.z - udm.z; acc1 = fmaf(dx * dx, sd2, acc1); }
        { const float dx = udp.w - udm.w; acc1 = fmaf(dx * dx, sd2, acc1); }

        // ---- W axis: neighbors via shfl on u(h) within 32-lane groups ----
        const float ulw = __shfl_up(uc.w, 1, 32);
        const float urx = __shfl_down(uc.x, 1, 32);
        const float ul = (w4 == 0)  ? uc.x : ulw;
        const float ur = (w4 == 31) ? uc.w : urx;
        { const float dx = uc.y - ul;   acc2 = fmaf(dx * dx, sw02, acc2); }
        { const float dx = uc.z - uc.x; acc2 = fmaf(dx * dx, 0.25f, acc2); }
        { const float dx = uc.w - uc.y; acc2 = fmaf(dx * dx, 0.25f, acc2); }
        { const float dx = ur - uc.z;   acc2 = fmaf(dx * dx, sw32, acc2); }

        // ---- H axis: u(h+1) - u(h-1) in registers ----
        const float4 un = sub4(xn, tn);
        const float sh2 = (h == 0 || h == Hn - 1) ? 1.0f : 0.25f;
        { const float dx = un.x - um.x; acc0 = fmaf(dx * dx, sh2, acc0); }
        { const float dx = un.y - um.y; acc0 = fmaf(dx * dx, sh2, acc0); }
        { const float dx = un.z - um.z; acc0 = fmaf(dx * dx, sh2, acc0); }
        { const float dx = un.w - um.w; acc0 = fmaf(dx * dx, sh2, acc0); }

        // slide windows
        um = uc; uc = un;
        if (isHalo) hu = sub4(xh, th);
        Xr += ROW; Tr += ROW;
        s ^= 1;
    }

    float acc = (acc0 + acc1) + acc2;

    // wave (64-lane) reduction
    for (int off = 32; off > 0; off >>= 1)
        acc += __shfl_down(acc, off, 64);

    __shared__ float wsum[NTHREADS / 64];
    const int lane = tid & 63;
    const int wid = tid >> 6;
    if (lane == 0) wsum[wid] = acc;
    __syncthreads();
    if (tid == 0) {
        double bsum = (double)wsum[0] + (double)wsum[1] +
                      (double)wsum[2] + (double)wsum[3];
        partials[blockIdx.x] = bsum;
    }
}

__global__ __launch_bounds__(256) void gradloss_reduce(
        const double* __restrict__ partials, float* __restrict__ out, int n) {
    double a = 0.0;
    for (int i = threadIdx.x; i < n; i += 256) a += partials[i];
    for (int off = 32; off > 0; off >>= 1)
        a += __shfl_down(a, off, 64);
    __shared__ double sh[4];
    const int lane = threadIdx.x & 63;
    const int wid = threadIdx.x >> 6;
    if (lane == 0) sh[wid] = a;
    __syncthreads();
    if (threadIdx.x == 0) {
        double tot = sh[0] + sh[1] + sh[2] + sh[3];
        out[0] = (float)(tot / 8388608.0);  // / (B*D*H*W)
    }
}

extern "C" void kernel_launch(void* const* d_in, const int* in_sizes, int n_in,
                              void* d_out, int out_size, void* d_ws, size_t ws_size,
                              hipStream_t stream) {
    const float* x = (const float*)d_in[0];
    const float* t = (const float*)d_in[1];
    float* out = (float*)d_out;
    double* partials = (double*)d_ws;  // NBLOCKS * 8 B = 32 KiB of d_ws

    gradloss_main<<<NBLOCKS, NTHREADS, 0, stream>>>(x, t, partials);
    gradloss_reduce<<<1, 256, 0, stream>>>(partials, out, NBLOCKS);
}